// Round 3
// baseline (856.653 us; speedup 1.0000x reference)
//
#include <hip/hip_runtime.h>
#include <math.h>
#include <float.h>

#define N_NODES 50000
#define N_EDGES 800000
#define D 64
#define NPART 128
#define ROWS_PER 391            // 128 * 391 = 50048 >= 50000
#define NV4 (N_EDGES / 4)       // 200000 exact

static inline size_t align_up(size_t x, size_t a) { return (x + a - 1) & ~(a - 1); }

// Edges are sorted by (e0, e1) (np.unique). So e0 is non-decreasing:
// offsA[v] = lower_bound(e0, v) via boundary detection — atomic-free.
__global__ void k_offsA(const int* __restrict__ e0, int* __restrict__ offsA) {
    int j = blockIdx.x * blockDim.x + threadIdx.x;
    if (j > N_EDGES) return;
    if (j == 0) {
        int b = e0[0];
        for (int v = 0; v <= b; ++v) offsA[v] = 0;
    } else if (j == N_EDGES) {
        int a = e0[N_EDGES - 1];
        for (int v = a + 1; v <= N_NODES; ++v) offsA[v] = N_EDGES;
    } else {
        int a = e0[j - 1], b = e0[j];
        for (int v = a + 1; v <= b; ++v) offsA[v] = j;
    }
}

// Partitioned LDS histogram of e1 (rows of the second directed half).
// Block p exclusively owns rows [p*ROWS_PER, ...) -> coalesced degB writes,
// zero global atomics, zero cross-XCD line sharing.
__global__ __launch_bounds__(1024) void k_hist(const int* __restrict__ e1,
                                               int* __restrict__ degB) {
    __shared__ int bins[ROWS_PER];
    int r0 = blockIdx.x * ROWS_PER;
    int nr = min(N_NODES - r0, ROWS_PER);
    if (nr <= 0) return;
    for (int i = threadIdx.x; i < nr; i += 1024) bins[i] = 0;
    __syncthreads();
    const int4* v = (const int4*)e1;
    for (int i = threadIdx.x; i < NV4; i += 1024) {
        int4 q = v[i];
        if ((unsigned)(q.x - r0) < (unsigned)nr) atomicAdd(&bins[q.x - r0], 1);
        if ((unsigned)(q.y - r0) < (unsigned)nr) atomicAdd(&bins[q.y - r0], 1);
        if ((unsigned)(q.z - r0) < (unsigned)nr) atomicAdd(&bins[q.z - r0], 1);
        if ((unsigned)(q.w - r0) < (unsigned)nr) atomicAdd(&bins[q.w - r0], 1);
    }
    __syncthreads();
    for (int i = threadIdx.x; i < nr; i += 1024) degB[r0 + i] = bins[i];
}

__global__ void k_scan1(const int* __restrict__ deg, int* __restrict__ offs,
                        int* __restrict__ bsum) {
    __shared__ int s[1024];
    int tid = threadIdx.x;
    int i = blockIdx.x * 1024 + tid;
    int v = (i < N_NODES) ? deg[i] : 0;
    s[tid] = v;
    __syncthreads();
    for (int d = 1; d < 1024; d <<= 1) {
        int t = (tid >= d) ? s[tid - d] : 0;
        __syncthreads();
        v += t;
        s[tid] = v;
        __syncthreads();
    }
    if (i < N_NODES) offs[i + 1] = v;   // inclusive within block
    if (tid == 1023) bsum[blockIdx.x] = v;
}

__global__ void k_scan2(int* __restrict__ bsum, int nb) {
    __shared__ int s[64];
    int tid = threadIdx.x;
    if (tid < nb) s[tid] = bsum[tid];
    __syncthreads();
    if (tid == 0) {
        int run = 0;
        for (int b = 0; b < nb; ++b) { int t = s[b]; s[b] = run; run += t; }
    }
    __syncthreads();
    if (tid < nb) bsum[tid] = s[tid];
}

__global__ void k_scan3(int* __restrict__ offs, const int* __restrict__ bsum) {
    int i = blockIdx.x * blockDim.x + threadIdx.x;
    if (i == 0) offs[0] = 0;
    if (i < N_NODES) offs[i + 1] += bsum[i >> 10];
}

// Partitioned fill: block p owns rows [r0, r0+nr); LDS cursors seeded from
// offsB; every adjB line written by exactly one block. No global atomics.
__global__ __launch_bounds__(1024) void k_fill2(const int* __restrict__ e0,
                                                const int* __restrict__ e1,
                                                const int* __restrict__ offsB,
                                                int* __restrict__ adjB) {
    __shared__ int cur[ROWS_PER];
    int r0 = blockIdx.x * ROWS_PER;
    int nr = min(N_NODES - r0, ROWS_PER);
    if (nr <= 0) return;
    for (int i = threadIdx.x; i < nr; i += 1024) cur[i] = offsB[r0 + i];
    __syncthreads();
    const int4* vr = (const int4*)e1;
    const int4* vc = (const int4*)e0;
    for (int i = threadIdx.x; i < NV4; i += 1024) {
        int4 r = vr[i];
        int4 c = vc[i];
        if ((unsigned)(r.x - r0) < (unsigned)nr) adjB[atomicAdd(&cur[r.x - r0], 1)] = c.x;
        if ((unsigned)(r.y - r0) < (unsigned)nr) adjB[atomicAdd(&cur[r.y - r0], 1)] = c.y;
        if ((unsigned)(r.z - r0) < (unsigned)nr) adjB[atomicAdd(&cur[r.z - r0], 1)] = c.z;
        if ((unsigned)(r.w - r0) < (unsigned)nr) adjB[atomicAdd(&cur[r.w - r0], 1)] = c.w;
    }
}

// One wave per node: sum/max over both neighbor lists + fused attention mix.
// Pass A neighbors: e1[offsA[v]..offsA[v+1])  (contiguous, no build needed)
// Pass B neighbors: adjB[offsB[v]..offsB[v+1])
__global__ void k_agg(const float* __restrict__ h, const int* __restrict__ offsA,
                      const int* __restrict__ e1, const int* __restrict__ offsB,
                      const int* __restrict__ adjB, const float* __restrict__ att_w,
                      const float* __restrict__ att_b, float* __restrict__ xbuf) {
    int wid = (blockIdx.x * blockDim.x + threadIdx.x) >> 6;
    int lane = threadIdx.x & 63;
    int sA = offsA[wid], eA = offsA[wid + 1];
    int sB = offsB[wid], eB = offsB[wid + 1];
    float sum = 0.f, mx = -FLT_MAX;
    for (int pass = 0; pass < 2; ++pass) {
        const int* lst = pass ? adjB : e1;
        int e = pass ? sB : sA;
        int end = pass ? eB : eA;
        for (; e + 4 <= end; e += 4) {
            int c0 = lst[e], c1 = lst[e + 1], c2 = lst[e + 2], c3 = lst[e + 3];
            float v0 = h[c0 * D + lane];
            float v1 = h[c1 * D + lane];
            float v2 = h[c2 * D + lane];
            float v3 = h[c3 * D + lane];
            sum += v0 + v1 + v2 + v3;
            mx = fmaxf(mx, fmaxf(fmaxf(v0, v1), fmaxf(v2, v3)));
        }
        for (; e < end; ++e) {
            float v = h[lst[e] * D + lane];
            sum += v;
            mx = fmaxf(mx, v);
        }
    }
    if ((eA - sA) + (eB - sB) == 0) mx = 0.f;

    float aw00 = att_w[lane * 2 + 0], aw01 = att_w[lane * 2 + 1];
    float aw10 = att_w[(D + lane) * 2 + 0], aw11 = att_w[(D + lane) * 2 + 1];
    float p0 = sum * aw00 + mx * aw10;
    float p1 = sum * aw01 + mx * aw11;
    for (int o = 32; o > 0; o >>= 1) {
        p0 += __shfl_xor(p0, o);
        p1 += __shfl_xor(p1, o);
    }
    float s0 = p0 + att_b[0], s1 = p1 + att_b[1];
    float m = fmaxf(s0, s1);
    float e0v = expf(s0 - m), e1v = expf(s1 - m);
    float inv = 1.f / (e0v + e1v);
    float w0 = e0v * inv, w1 = e1v * inv;
    xbuf[wid * D + lane] = h[wid * D + lane] + w0 * sum + w1 * mx;
}

// Fused 3-layer MLP on 64-row tiles. LDS: x-tile, y-tile, one weight buffer.
__global__ __launch_bounds__(256) void k_dense(const float* __restrict__ xbuf,
        const float* __restrict__ w1, const float* __restrict__ b1,
        const float* __restrict__ w2, const float* __restrict__ b2,
        const float* __restrict__ w3, const float* __restrict__ b3,
        float* __restrict__ out) {
    __shared__ float xt[64 * 64];
    __shared__ float yt[64 * 64];
    __shared__ float wb[64 * 64];
    int tid = threadIdx.x;
    int base = blockIdx.x * 64;

    for (int i = tid; i < 64 * 64; i += 256) {
        int r = base + (i >> 6);
        xt[i] = (r < N_NODES) ? xbuf[(size_t)base * 64 + i] : 0.f;
    }
    for (int i = tid; i < 64 * 64; i += 256) wb[i] = w1[i];
    __syncthreads();

    int wave = tid >> 6, lane = tid & 63;
    float bias = b1[lane];
    for (int rr = 0; rr < 16; ++rr) {
        int r = wave * 16 + rr;
        float acc = bias;
#pragma unroll
        for (int k = 0; k < 64; ++k) acc += xt[r * 64 + k] * wb[k * 64 + lane];
        yt[r * 64 + lane] = fmaxf(acc, 0.f);
    }
    __syncthreads();
    for (int i = tid; i < 64 * 64; i += 256) wb[i] = w2[i];
    __syncthreads();
    bias = b2[lane];
    for (int rr = 0; rr < 16; ++rr) {
        int r = wave * 16 + rr;
        float acc = bias;
#pragma unroll
        for (int k = 0; k < 64; ++k) acc += yt[r * 64 + k] * wb[k * 64 + lane];
        xt[r * 64 + lane] = fmaxf(acc, 0.f);
    }
    __syncthreads();
    for (int i = tid; i < 64 * 64; i += 256) wb[i] = w3[i];
    __syncthreads();
    bias = b3[lane];
    for (int rr = 0; rr < 16; ++rr) {
        int r = wave * 16 + rr;
        int gr = base + r;
        if (gr >= N_NODES) continue;
        float acc = bias;
#pragma unroll
        for (int k = 0; k < 64; ++k) acc += xt[r * 64 + k] * wb[k * 64 + lane];
        out[(size_t)gr * 64 + lane] = acc;
    }
}

extern "C" void kernel_launch(void* const* d_in, const int* in_sizes, int n_in,
                              void* d_out, int out_size, void* d_ws, size_t ws_size,
                              hipStream_t stream) {
    const float* h     = (const float*)d_in[0];
    const int*   ei    = (const int*)d_in[1];
    const float* att_w = (const float*)d_in[2];
    const float* att_b = (const float*)d_in[3];
    const float* w1    = (const float*)d_in[4];
    const float* b1    = (const float*)d_in[5];
    const float* w2    = (const float*)d_in[6];
    const float* b2    = (const float*)d_in[7];
    const float* w3    = (const float*)d_in[8];
    const float* b3    = (const float*)d_in[9];
    float* out = (float*)d_out;

    const int* e0 = ei;             // lo, sorted non-decreasing
    const int* e1 = ei + N_EDGES;   // hi

    char* ws = (char*)d_ws;
    size_t off = 0;
    auto alloc = [&](size_t bytes) {
        char* p = ws + off;
        off = align_up(off + bytes, 256);
        return p;
    };
    int* offsA = (int*)alloc((size_t)(N_NODES + 1) * 4);
    int* degB  = (int*)alloc((size_t)N_NODES * 4);
    int* offsB = (int*)alloc((size_t)(N_NODES + 1) * 4);
    int* bsum  = (int*)alloc(64 * 4);
    int* adjB  = (int*)alloc((size_t)N_EDGES * 4);
    float* xbuf = (float*)alloc((size_t)N_NODES * D * 4);
    // ~16.6 MB total; no memsets needed (every buffer fully written)

    int nb = (N_NODES + 1023) / 1024;   // 49
    k_offsA<<<(N_EDGES + 256) / 256, 256, 0, stream>>>(e0, offsA);
    k_hist <<<NPART, 1024, 0, stream>>>(e1, degB);
    k_scan1<<<nb, 1024, 0, stream>>>(degB, offsB, bsum);
    k_scan2<<<1, 64, 0, stream>>>(bsum, nb);
    k_scan3<<<(N_NODES + 255) / 256, 256, 0, stream>>>(offsB, bsum);
    k_fill2<<<NPART, 1024, 0, stream>>>(e0, e1, offsB, adjB);
    k_agg  <<<(N_NODES * 64) / 256, 256, 0, stream>>>(h, offsA, e1, offsB, adjB,
                                                      att_w, att_b, xbuf);
    k_dense<<<(N_NODES + 63) / 64, 256, 0, stream>>>(xbuf, w1, b1, w2, b2, w3, b3, out);
}

// Round 8
// 392.025 us; speedup vs baseline: 2.1852x; 2.1852x over previous
//
#include <hip/hip_runtime.h>
#include <math.h>
#include <float.h>

#define N_NODES 50000
#define N_EDGES 800000
#define D 64
#define NPART 128
#define ROWS_PER 391            // 128 * 391 = 50048 >= 50000
#define NV4 (N_EDGES / 4)       // 200000 exact

static inline size_t align_up(size_t x, size_t a) { return (x + a - 1) & ~(a - 1); }

// Edges sorted by (e0, e1) (np.unique). offsA[v] = lower_bound(e0, v).
// Per-node binary search: fully parallel, L2-hot. (Boundary-detection version
// had a single thread serially writing the ~37k-entry tail -> 472 us.)
__global__ void k_offsA(const int* __restrict__ e0, int* __restrict__ offsA) {
    int v = blockIdx.x * blockDim.x + threadIdx.x;
    if (v > N_NODES) return;
    int lo = 0, hi = N_EDGES;
    while (lo < hi) {
        int mid = (lo + hi) >> 1;
        if (e0[mid] < v) lo = mid + 1; else hi = mid;
    }
    offsA[v] = lo;
}

// Partitioned LDS histogram of e1 (rows of the second directed half).
// Block p exclusively owns rows [p*ROWS_PER, ...) -> coalesced degB writes,
// zero global atomics, zero cross-XCD line sharing.
__global__ __launch_bounds__(1024) void k_hist(const int* __restrict__ e1,
                                               int* __restrict__ degB) {
    __shared__ int bins[ROWS_PER];
    int r0 = blockIdx.x * ROWS_PER;
    int nr = min(N_NODES - r0, ROWS_PER);
    if (nr <= 0) return;
    for (int i = threadIdx.x; i < nr; i += 1024) bins[i] = 0;
    __syncthreads();
    const int4* v = (const int4*)e1;
    for (int i = threadIdx.x; i < NV4; i += 1024) {
        int4 q = v[i];
        if ((unsigned)(q.x - r0) < (unsigned)nr) atomicAdd(&bins[q.x - r0], 1);
        if ((unsigned)(q.y - r0) < (unsigned)nr) atomicAdd(&bins[q.y - r0], 1);
        if ((unsigned)(q.z - r0) < (unsigned)nr) atomicAdd(&bins[q.z - r0], 1);
        if ((unsigned)(q.w - r0) < (unsigned)nr) atomicAdd(&bins[q.w - r0], 1);
    }
    __syncthreads();
    for (int i = threadIdx.x; i < nr; i += 1024) degB[r0 + i] = bins[i];
}

__global__ void k_scan1(const int* __restrict__ deg, int* __restrict__ offs,
                        int* __restrict__ bsum) {
    __shared__ int s[1024];
    int tid = threadIdx.x;
    int i = blockIdx.x * 1024 + tid;
    int v = (i < N_NODES) ? deg[i] : 0;
    s[tid] = v;
    __syncthreads();
    for (int d = 1; d < 1024; d <<= 1) {
        int t = (tid >= d) ? s[tid - d] : 0;
        __syncthreads();
        v += t;
        s[tid] = v;
        __syncthreads();
    }
    if (i < N_NODES) offs[i + 1] = v;   // inclusive within block
    if (tid == 1023) bsum[blockIdx.x] = v;
}

__global__ void k_scan2(int* __restrict__ bsum, int nb) {
    __shared__ int s[64];
    int tid = threadIdx.x;
    if (tid < nb) s[tid] = bsum[tid];
    __syncthreads();
    if (tid == 0) {
        int run = 0;
        for (int b = 0; b < nb; ++b) { int t = s[b]; s[b] = run; run += t; }
    }
    __syncthreads();
    if (tid < nb) bsum[tid] = s[tid];
}

__global__ void k_scan3(int* __restrict__ offs, const int* __restrict__ bsum) {
    int i = blockIdx.x * blockDim.x + threadIdx.x;
    if (i == 0) offs[0] = 0;
    if (i < N_NODES) offs[i + 1] += bsum[i >> 10];
}

// Partitioned fill: block p owns rows [r0, r0+nr); LDS cursors seeded from
// offsB; every adjB line written by exactly one block. No global atomics.
__global__ __launch_bounds__(1024) void k_fill2(const int* __restrict__ e0,
                                                const int* __restrict__ e1,
                                                const int* __restrict__ offsB,
                                                int* __restrict__ adjB) {
    __shared__ int cur[ROWS_PER];
    int r0 = blockIdx.x * ROWS_PER;
    int nr = min(N_NODES - r0, ROWS_PER);
    if (nr <= 0) return;
    for (int i = threadIdx.x; i < nr; i += 1024) cur[i] = offsB[r0 + i];
    __syncthreads();
    const int4* vr = (const int4*)e1;
    const int4* vc = (const int4*)e0;
    for (int i = threadIdx.x; i < NV4; i += 1024) {
        int4 r = vr[i];
        int4 c = vc[i];
        if ((unsigned)(r.x - r0) < (unsigned)nr) adjB[atomicAdd(&cur[r.x - r0], 1)] = c.x;
        if ((unsigned)(r.y - r0) < (unsigned)nr) adjB[atomicAdd(&cur[r.y - r0], 1)] = c.y;
        if ((unsigned)(r.z - r0) < (unsigned)nr) adjB[atomicAdd(&cur[r.z - r0], 1)] = c.z;
        if ((unsigned)(r.w - r0) < (unsigned)nr) adjB[atomicAdd(&cur[r.w - r0], 1)] = c.w;
    }
}

// One wave per node: sum/max over both neighbor lists + fused attention mix.
// Pass A neighbors: e1[offsA[v]..offsA[v+1])  (contiguous, no build needed)
// Pass B neighbors: adjB[offsB[v]..offsB[v+1])
__global__ void k_agg(const float* __restrict__ h, const int* __restrict__ offsA,
                      const int* __restrict__ e1, const int* __restrict__ offsB,
                      const int* __restrict__ adjB, const float* __restrict__ att_w,
                      const float* __restrict__ att_b, float* __restrict__ xbuf) {
    int wid = (blockIdx.x * blockDim.x + threadIdx.x) >> 6;
    int lane = threadIdx.x & 63;
    int sA = offsA[wid], eA = offsA[wid + 1];
    int sB = offsB[wid], eB = offsB[wid + 1];
    float sum = 0.f, mx = -FLT_MAX;
    for (int pass = 0; pass < 2; ++pass) {
        const int* lst = pass ? adjB : e1;
        int e = pass ? sB : sA;
        int end = pass ? eB : eA;
        for (; e + 4 <= end; e += 4) {
            int c0 = lst[e], c1 = lst[e + 1], c2 = lst[e + 2], c3 = lst[e + 3];
            float v0 = h[c0 * D + lane];
            float v1 = h[c1 * D + lane];
            float v2 = h[c2 * D + lane];
            float v3 = h[c3 * D + lane];
            sum += v0 + v1 + v2 + v3;
            mx = fmaxf(mx, fmaxf(fmaxf(v0, v1), fmaxf(v2, v3)));
        }
        for (; e < end; ++e) {
            float v = h[lst[e] * D + lane];
            sum += v;
            mx = fmaxf(mx, v);
        }
    }
    if ((eA - sA) + (eB - sB) == 0) mx = 0.f;

    float aw00 = att_w[lane * 2 + 0], aw01 = att_w[lane * 2 + 1];
    float aw10 = att_w[(D + lane) * 2 + 0], aw11 = att_w[(D + lane) * 2 + 1];
    float p0 = sum * aw00 + mx * aw10;
    float p1 = sum * aw01 + mx * aw11;
    for (int o = 32; o > 0; o >>= 1) {
        p0 += __shfl_xor(p0, o);
        p1 += __shfl_xor(p1, o);
    }
    float s0 = p0 + att_b[0], s1 = p1 + att_b[1];
    float m = fmaxf(s0, s1);
    float e0v = expf(s0 - m), e1v = expf(s1 - m);
    float inv = 1.f / (e0v + e1v);
    float w0 = e0v * inv, w1 = e1v * inv;
    xbuf[wid * D + lane] = h[wid * D + lane] + w0 * sum + w1 * mx;
}

// Fused 3-layer MLP on 64-row tiles. LDS: x-tile, y-tile, one weight buffer.
__global__ __launch_bounds__(256) void k_dense(const float* __restrict__ xbuf,
        const float* __restrict__ w1, const float* __restrict__ b1,
        const float* __restrict__ w2, const float* __restrict__ b2,
        const float* __restrict__ w3, const float* __restrict__ b3,
        float* __restrict__ out) {
    __shared__ float xt[64 * 64];
    __shared__ float yt[64 * 64];
    __shared__ float wb[64 * 64];
    int tid = threadIdx.x;
    int base = blockIdx.x * 64;

    for (int i = tid; i < 64 * 64; i += 256) {
        int r = base + (i >> 6);
        xt[i] = (r < N_NODES) ? xbuf[(size_t)base * 64 + i] : 0.f;
    }
    for (int i = tid; i < 64 * 64; i += 256) wb[i] = w1[i];
    __syncthreads();

    int wave = tid >> 6, lane = tid & 63;
    float bias = b1[lane];
    for (int rr = 0; rr < 16; ++rr) {
        int r = wave * 16 + rr;
        float acc = bias;
#pragma unroll
        for (int k = 0; k < 64; ++k) acc += xt[r * 64 + k] * wb[k * 64 + lane];
        yt[r * 64 + lane] = fmaxf(acc, 0.f);
    }
    __syncthreads();
    for (int i = tid; i < 64 * 64; i += 256) wb[i] = w2[i];
    __syncthreads();
    bias = b2[lane];
    for (int rr = 0; rr < 16; ++rr) {
        int r = wave * 16 + rr;
        float acc = bias;
#pragma unroll
        for (int k = 0; k < 64; ++k) acc += yt[r * 64 + k] * wb[k * 64 + lane];
        xt[r * 64 + lane] = fmaxf(acc, 0.f);
    }
    __syncthreads();
    for (int i = tid; i < 64 * 64; i += 256) wb[i] = w3[i];
    __syncthreads();
    bias = b3[lane];
    for (int rr = 0; rr < 16; ++rr) {
        int r = wave * 16 + rr;
        int gr = base + r;
        if (gr >= N_NODES) continue;
        float acc = bias;
#pragma unroll
        for (int k = 0; k < 64; ++k) acc += xt[r * 64 + k] * wb[k * 64 + lane];
        out[(size_t)gr * 64 + lane] = acc;
    }
}

extern "C" void kernel_launch(void* const* d_in, const int* in_sizes, int n_in,
                              void* d_out, int out_size, void* d_ws, size_t ws_size,
                              hipStream_t stream) {
    const float* h     = (const float*)d_in[0];
    const int*   ei    = (const int*)d_in[1];
    const float* att_w = (const float*)d_in[2];
    const float* att_b = (const float*)d_in[3];
    const float* w1    = (const float*)d_in[4];
    const float* b1    = (const float*)d_in[5];
    const float* w2    = (const float*)d_in[6];
    const float* b2    = (const float*)d_in[7];
    const float* w3    = (const float*)d_in[8];
    const float* b3    = (const float*)d_in[9];
    float* out = (float*)d_out;

    const int* e0 = ei;             // lo, sorted non-decreasing
    const int* e1 = ei + N_EDGES;   // hi

    char* ws = (char*)d_ws;
    size_t off = 0;
    auto alloc = [&](size_t bytes) {
        char* p = ws + off;
        off = align_up(off + bytes, 256);
        return p;
    };
    int* offsA = (int*)alloc((size_t)(N_NODES + 1) * 4);
    int* degB  = (int*)alloc((size_t)N_NODES * 4);
    int* offsB = (int*)alloc((size_t)(N_NODES + 1) * 4);
    int* bsum  = (int*)alloc(64 * 4);
    int* adjB  = (int*)alloc((size_t)N_EDGES * 4);
    float* xbuf = (float*)alloc((size_t)N_NODES * D * 4);
    // ~16.6 MB total; no memsets needed (every buffer fully written)

    int nb = (N_NODES + 1023) / 1024;   // 49
    k_offsA<<<(N_NODES + 256) / 256, 256, 0, stream>>>(e0, offsA);
    k_hist <<<NPART, 1024, 0, stream>>>(e1, degB);
    k_scan1<<<nb, 1024, 0, stream>>>(degB, offsB, bsum);
    k_scan2<<<1, 64, 0, stream>>>(bsum, nb);
    k_scan3<<<(N_NODES + 255) / 256, 256, 0, stream>>>(offsB, bsum);
    k_fill2<<<NPART, 1024, 0, stream>>>(e0, e1, offsB, adjB);
    k_agg  <<<(N_NODES * 64) / 256, 256, 0, stream>>>(h, offsA, e1, offsB, adjB,
                                                      att_w, att_b, xbuf);
    k_dense<<<(N_NODES + 63) / 64, 256, 0, stream>>>(xbuf, w1, b1, w2, b2, w3, b3, out);
}

// Round 13
// 235.429 us; speedup vs baseline: 3.6387x; 1.6651x over previous
//
#include <hip/hip_runtime.h>
#include <math.h>
#include <float.h>

#define N_NODES 50000
#define N_EDGES 800000
#define D 64

// Bucket-partition build of the B-direction CSR (rows = hi = e1).
#define NCH 1024                  // chunk blocks
#define CHUNK 782                 // ceil(800000/1024)
#define PART_SHIFT 9
#define PROWS 512                 // rows per part (1<<PART_SHIFT)
#define NPART_B 98                // ceil(50000/512)
#define CNT_LEN (NPART_B * NCH)   // 100352 = 98*1024 (divisible by 1024)

static inline size_t align_up(size_t x, size_t a) { return (x + a - 1) & ~(a - 1); }

// Edges sorted by (e0, e1) (np.unique). offsA[v] = lower_bound(e0, v).
__global__ void k_offsA(const int* __restrict__ e0, int* __restrict__ offsA) {
    int v = blockIdx.x * blockDim.x + threadIdx.x;
    if (v > N_NODES) return;
    int lo = 0, hi = N_EDGES;
    while (lo < hi) {
        int mid = (lo + hi) >> 1;
        if (e0[mid] < v) lo = mid + 1; else hi = mid;
    }
    offsA[v] = lo;
}

// Phase 1: per-chunk count of edges per part (part = hi >> 9).
__global__ __launch_bounds__(256) void k_count(const int* __restrict__ e1,
                                               int* __restrict__ countsG) {
    __shared__ int cnt[NPART_B];
    for (int i = threadIdx.x; i < NPART_B; i += 256) cnt[i] = 0;
    __syncthreads();
    int s = blockIdx.x * CHUNK;
    int e = min(s + CHUNK, N_EDGES);
    for (int j = s + threadIdx.x; j < e; j += 256)
        atomicAdd(&cnt[e1[j] >> PART_SHIFT], 1);
    __syncthreads();
    for (int p = threadIdx.x; p < NPART_B; p += 256)
        countsG[p * NCH + blockIdx.x] = cnt[p];
}

// Generic 3-kernel exclusive scan (length L, L padded ok). cbase[i] = sum of first i.
__global__ void k_scan1(const int* __restrict__ deg, int* __restrict__ offs,
                        int* __restrict__ bsum, int L) {
    __shared__ int s[1024];
    int tid = threadIdx.x;
    int i = blockIdx.x * 1024 + tid;
    int v = (i < L) ? deg[i] : 0;
    s[tid] = v;
    __syncthreads();
    for (int d = 1; d < 1024; d <<= 1) {
        int t = (tid >= d) ? s[tid - d] : 0;
        __syncthreads();
        v += t;
        s[tid] = v;
        __syncthreads();
    }
    if (i < L) offs[i + 1] = v;   // inclusive within block
    if (tid == 1023) bsum[blockIdx.x] = v;
}

__global__ void k_scan2(int* __restrict__ bsum, int nb) {
    __shared__ int s[128];
    int tid = threadIdx.x;
    if (tid < nb) s[tid] = bsum[tid];
    __syncthreads();
    if (tid == 0) {
        int run = 0;
        for (int b = 0; b < nb; ++b) { int t = s[b]; s[b] = run; run += t; }
    }
    __syncthreads();
    if (tid < nb) bsum[tid] = s[tid];
}

__global__ void k_scan3(int* __restrict__ offs, const int* __restrict__ bsum, int L) {
    int i = blockIdx.x * blockDim.x + threadIdx.x;
    if (i == 0) offs[0] = 0;
    if (i < L) offs[i + 1] += bsum[i >> 10];
}

// Phase 3: scatter edges into part-major buckets. Each (part, chunk) region is
// exclusively owned by one block -> no global atomics, no cross-XCD line churn.
__global__ __launch_bounds__(256) void k_scatter(const int* __restrict__ e0,
                                                 const int* __restrict__ e1,
                                                 const int* __restrict__ cbase,
                                                 unsigned* __restrict__ bucket) {
    __shared__ int cur[NPART_B];
    for (int i = threadIdx.x; i < NPART_B; i += 256)
        cur[i] = cbase[i * NCH + blockIdx.x];
    __syncthreads();
    int s = blockIdx.x * CHUNK;
    int e = min(s + CHUNK, N_EDGES);
    for (int j = s + threadIdx.x; j < e; j += 256) {
        int hi = e1[j], lo = e0[j];
        int pos = atomicAdd(&cur[hi >> PART_SHIFT], 1);
        bucket[pos] = ((unsigned)hi << 16) | (unsigned)lo;   // ids < 65536
    }
}

// Phase 4: per-part CSR. Block p scans only its ~8k-edge segment.
__global__ __launch_bounds__(1024) void k_csrB(const unsigned* __restrict__ bucket,
                                               const int* __restrict__ cbase,
                                               int* __restrict__ offsB,
                                               int* __restrict__ adjB) {
    __shared__ int bins[PROWS];
    __shared__ int excl[PROWS];
    __shared__ int cur[PROWS];
    int p = blockIdx.x;
    int segS = cbase[p * NCH];
    int segE = (p + 1 < NPART_B) ? cbase[(p + 1) * NCH] : N_EDGES;
    int r0 = p << PART_SHIFT;
    for (int i = threadIdx.x; i < PROWS; i += 1024) bins[i] = 0;
    __syncthreads();
    for (int j = segS + threadIdx.x; j < segE; j += 1024)
        atomicAdd(&bins[(int)(bucket[j] >> 16) - r0], 1);
    __syncthreads();
    if (threadIdx.x < PROWS) excl[threadIdx.x] = bins[threadIdx.x];
    __syncthreads();
    for (int d = 1; d < PROWS; d <<= 1) {   // Hillis-Steele inclusive scan
        int t = 0;
        if (threadIdx.x < PROWS && threadIdx.x >= d) t = excl[threadIdx.x - d];
        __syncthreads();
        if (threadIdx.x < PROWS) excl[threadIdx.x] += t;
        __syncthreads();
    }
    if (threadIdx.x < PROWS) {
        int st = segS + excl[threadIdx.x] - bins[threadIdx.x];   // exclusive start
        cur[threadIdx.x] = st;
        int v = r0 + threadIdx.x;
        if (v < N_NODES) offsB[v] = st;
    }
    if (p == NPART_B - 1 && threadIdx.x == 0) offsB[N_NODES] = N_EDGES;
    __syncthreads();
    for (int j = segS + threadIdx.x; j < segE; j += 1024) {
        unsigned pk = bucket[j];
        int pos = atomicAdd(&cur[(int)(pk >> 16) - r0], 1);
        adjB[pos] = (int)(pk & 0xFFFFu);
    }
}

// One wave per node: sum/max over both neighbor lists + fused attention mix.
// A neighbors: e1[offsA[v]..offsA[v+1]) (contiguous, sorted input, no build)
// B neighbors: adjB[offsB[v]..offsB[v+1])
__global__ void k_agg(const float* __restrict__ h, const int* __restrict__ offsA,
                      const int* __restrict__ e1, const int* __restrict__ offsB,
                      const int* __restrict__ adjB, const float* __restrict__ att_w,
                      const float* __restrict__ att_b, float* __restrict__ xbuf) {
    int wid = (blockIdx.x * blockDim.x + threadIdx.x) >> 6;
    int lane = threadIdx.x & 63;
    int sA = offsA[wid], eA = offsA[wid + 1];
    int sB = offsB[wid], eB = offsB[wid + 1];
    float sum = 0.f, mx = -FLT_MAX;
    for (int pass = 0; pass < 2; ++pass) {
        const int* lst = pass ? adjB : e1;
        int e = pass ? sB : sA;
        int end = pass ? eB : eA;
        for (; e + 4 <= end; e += 4) {
            int c0 = lst[e], c1 = lst[e + 1], c2 = lst[e + 2], c3 = lst[e + 3];
            float v0 = h[c0 * D + lane];
            float v1 = h[c1 * D + lane];
            float v2 = h[c2 * D + lane];
            float v3 = h[c3 * D + lane];
            sum += v0 + v1 + v2 + v3;
            mx = fmaxf(mx, fmaxf(fmaxf(v0, v1), fmaxf(v2, v3)));
        }
        for (; e < end; ++e) {
            float v = h[lst[e] * D + lane];
            sum += v;
            mx = fmaxf(mx, v);
        }
    }
    if ((eA - sA) + (eB - sB) == 0) mx = 0.f;

    float aw00 = att_w[lane * 2 + 0], aw01 = att_w[lane * 2 + 1];
    float aw10 = att_w[(D + lane) * 2 + 0], aw11 = att_w[(D + lane) * 2 + 1];
    float p0 = sum * aw00 + mx * aw10;
    float p1 = sum * aw01 + mx * aw11;
    for (int o = 32; o > 0; o >>= 1) {
        p0 += __shfl_xor(p0, o);
        p1 += __shfl_xor(p1, o);
    }
    float s0 = p0 + att_b[0], s1 = p1 + att_b[1];
    float m = fmaxf(s0, s1);
    float e0v = expf(s0 - m), e1v = expf(s1 - m);
    float inv = 1.f / (e0v + e1v);
    float w0 = e0v * inv, w1 = e1v * inv;
    xbuf[wid * D + lane] = h[wid * D + lane] + w0 * sum + w1 * mx;
}

// Fused 3-layer MLP on 64-row tiles. xbuf aliases out: each block reads its own
// 64 rows before overwriting them (block-local, safe).
__global__ __launch_bounds__(256) void k_dense(const float* __restrict__ xbuf,
        const float* __restrict__ w1, const float* __restrict__ b1,
        const float* __restrict__ w2, const float* __restrict__ b2,
        const float* __restrict__ w3, const float* __restrict__ b3,
        float* __restrict__ out) {
    __shared__ float xt[64 * 64];
    __shared__ float yt[64 * 64];
    __shared__ float wb[64 * 64];
    int tid = threadIdx.x;
    int base = blockIdx.x * 64;

    for (int i = tid; i < 64 * 64; i += 256) {
        int r = base + (i >> 6);
        xt[i] = (r < N_NODES) ? xbuf[(size_t)base * 64 + i] : 0.f;
    }
    for (int i = tid; i < 64 * 64; i += 256) wb[i] = w1[i];
    __syncthreads();

    int wave = tid >> 6, lane = tid & 63;
    float bias = b1[lane];
    for (int rr = 0; rr < 16; ++rr) {
        int r = wave * 16 + rr;
        float acc = bias;
#pragma unroll
        for (int k = 0; k < 64; ++k) acc += xt[r * 64 + k] * wb[k * 64 + lane];
        yt[r * 64 + lane] = fmaxf(acc, 0.f);
    }
    __syncthreads();
    for (int i = tid; i < 64 * 64; i += 256) wb[i] = w2[i];
    __syncthreads();
    bias = b2[lane];
    for (int rr = 0; rr < 16; ++rr) {
        int r = wave * 16 + rr;
        float acc = bias;
#pragma unroll
        for (int k = 0; k < 64; ++k) acc += yt[r * 64 + k] * wb[k * 64 + lane];
        xt[r * 64 + lane] = fmaxf(acc, 0.f);
    }
    __syncthreads();
    for (int i = tid; i < 64 * 64; i += 256) wb[i] = w3[i];
    __syncthreads();
    bias = b3[lane];
    for (int rr = 0; rr < 16; ++rr) {
        int r = wave * 16 + rr;
        int gr = base + r;
        if (gr >= N_NODES) continue;
        float acc = bias;
#pragma unroll
        for (int k = 0; k < 64; ++k) acc += xt[r * 64 + k] * wb[k * 64 + lane];
        out[(size_t)gr * 64 + lane] = acc;
    }
}

extern "C" void kernel_launch(void* const* d_in, const int* in_sizes, int n_in,
                              void* d_out, int out_size, void* d_ws, size_t ws_size,
                              hipStream_t stream) {
    const float* h     = (const float*)d_in[0];
    const int*   ei    = (const int*)d_in[1];
    const float* att_w = (const float*)d_in[2];
    const float* att_b = (const float*)d_in[3];
    const float* w1    = (const float*)d_in[4];
    const float* b1    = (const float*)d_in[5];
    const float* w2    = (const float*)d_in[6];
    const float* b2    = (const float*)d_in[7];
    const float* w3    = (const float*)d_in[8];
    const float* b3    = (const float*)d_in[9];
    float* out = (float*)d_out;

    const int* e0 = ei;             // lo, sorted non-decreasing
    const int* e1 = ei + N_EDGES;   // hi

    char* ws = (char*)d_ws;
    size_t off = 0;
    auto alloc = [&](size_t bytes) {
        char* p = ws + off;
        off = align_up(off + bytes, 256);
        return p;
    };
    int* offsA       = (int*)alloc((size_t)(N_NODES + 1) * 4);
    int* countsG     = (int*)alloc((size_t)CNT_LEN * 4);
    int* cbase       = (int*)alloc((size_t)(CNT_LEN + 1) * 4);
    int* bsum        = (int*)alloc(128 * 4);
    unsigned* bucket = (unsigned*)alloc((size_t)N_EDGES * 4);
    int* offsB       = (int*)alloc((size_t)(N_NODES + 1) * 4);
    int* adjB        = (int*)alloc((size_t)N_EDGES * 4);
    float* xbuf      = out;   // k_dense reads tile before overwriting (block-local)
    // ws use ~7.6 MB; every buffer fully written before read.

    int nbc = CNT_LEN / 1024;   // 98 exactly
    k_offsA  <<<(N_NODES + 256) / 256, 256, 0, stream>>>(e0, offsA);
    k_count  <<<NCH, 256, 0, stream>>>(e1, countsG);
    k_scan1  <<<nbc, 1024, 0, stream>>>(countsG, cbase, bsum, CNT_LEN);
    k_scan2  <<<1, 128, 0, stream>>>(bsum, nbc);
    k_scan3  <<<(CNT_LEN + 255) / 256, 256, 0, stream>>>(cbase, bsum, CNT_LEN);
    k_scatter<<<NCH, 256, 0, stream>>>(e0, e1, cbase, bucket);
    k_csrB   <<<NPART_B, 1024, 0, stream>>>(bucket, cbase, offsB, adjB);
    k_agg    <<<(N_NODES * 64) / 256, 256, 0, stream>>>(h, offsA, e1, offsB, adjB,
                                                        att_w, att_b, xbuf);
    k_dense  <<<(N_NODES + 63) / 64, 256, 0, stream>>>(xbuf, w1, b1, w2, b2, w3, b3, out);
}

// Round 15
// 215.393 us; speedup vs baseline: 3.9772x; 1.0930x over previous
//
#include <hip/hip_runtime.h>
#include <math.h>
#include <float.h>

#define N_NODES 50000
#define N_EDGES 800000
#define D 64

// Bucket-partition build of the B-direction CSR (rows = hi = e1).
#define NCH 1024                  // chunk blocks
#define CHUNK 782                 // ceil(800000/1024)
#define PART_SHIFT 9
#define PROWS 512                 // rows per part (1<<PART_SHIFT)
#define NPART_B 98                // ceil(50000/512)
#define CNT_LEN (NPART_B * NCH)   // 100352 = 98*1024 (divisible by 1024)

static inline size_t align_up(size_t x, size_t a) { return (x + a - 1) & ~(a - 1); }

__device__ __forceinline__ float lane_bcast(float v, int k) {
    return __uint_as_float(__builtin_amdgcn_readlane(__float_as_uint(v), k));
}

// Edges sorted by (e0, e1) (np.unique). offsA[v] = lower_bound(e0, v).
__global__ void k_offsA(const int* __restrict__ e0, int* __restrict__ offsA) {
    int v = blockIdx.x * blockDim.x + threadIdx.x;
    if (v > N_NODES) return;
    int lo = 0, hi = N_EDGES;
    while (lo < hi) {
        int mid = (lo + hi) >> 1;
        if (e0[mid] < v) lo = mid + 1; else hi = mid;
    }
    offsA[v] = lo;
}

// Phase 1: per-chunk count of edges per part (part = hi >> 9).
__global__ __launch_bounds__(256) void k_count(const int* __restrict__ e1,
                                               int* __restrict__ countsG) {
    __shared__ int cnt[NPART_B];
    for (int i = threadIdx.x; i < NPART_B; i += 256) cnt[i] = 0;
    __syncthreads();
    int s = blockIdx.x * CHUNK;
    int e = min(s + CHUNK, N_EDGES);
    for (int j = s + threadIdx.x; j < e; j += 256)
        atomicAdd(&cnt[e1[j] >> PART_SHIFT], 1);
    __syncthreads();
    for (int p = threadIdx.x; p < NPART_B; p += 256)
        countsG[p * NCH + blockIdx.x] = cnt[p];
}

// Generic 3-kernel exclusive scan (length L). cbase[i] = sum of first i.
__global__ void k_scan1(const int* __restrict__ deg, int* __restrict__ offs,
                        int* __restrict__ bsum, int L) {
    __shared__ int s[1024];
    int tid = threadIdx.x;
    int i = blockIdx.x * 1024 + tid;
    int v = (i < L) ? deg[i] : 0;
    s[tid] = v;
    __syncthreads();
    for (int d = 1; d < 1024; d <<= 1) {
        int t = (tid >= d) ? s[tid - d] : 0;
        __syncthreads();
        v += t;
        s[tid] = v;
        __syncthreads();
    }
    if (i < L) offs[i + 1] = v;   // inclusive within block
    if (tid == 1023) bsum[blockIdx.x] = v;
}

__global__ void k_scan2(int* __restrict__ bsum, int nb) {
    __shared__ int s[128];
    int tid = threadIdx.x;
    if (tid < nb) s[tid] = bsum[tid];
    __syncthreads();
    if (tid == 0) {
        int run = 0;
        for (int b = 0; b < nb; ++b) { int t = s[b]; s[b] = run; run += t; }
    }
    __syncthreads();
    if (tid < nb) bsum[tid] = s[tid];
}

__global__ void k_scan3(int* __restrict__ offs, const int* __restrict__ bsum, int L) {
    int i = blockIdx.x * blockDim.x + threadIdx.x;
    if (i == 0) offs[0] = 0;
    if (i < L) offs[i + 1] += bsum[i >> 10];
}

// Phase 3: scatter edges into part-major buckets. Each (part, chunk) region is
// exclusively owned by one block -> no global atomics, no cross-XCD line churn.
__global__ __launch_bounds__(256) void k_scatter(const int* __restrict__ e0,
                                                 const int* __restrict__ e1,
                                                 const int* __restrict__ cbase,
                                                 unsigned* __restrict__ bucket) {
    __shared__ int cur[NPART_B];
    for (int i = threadIdx.x; i < NPART_B; i += 256)
        cur[i] = cbase[i * NCH + blockIdx.x];
    __syncthreads();
    int s = blockIdx.x * CHUNK;
    int e = min(s + CHUNK, N_EDGES);
    for (int j = s + threadIdx.x; j < e; j += 256) {
        int hi = e1[j], lo = e0[j];
        int pos = atomicAdd(&cur[hi >> PART_SHIFT], 1);
        bucket[pos] = ((unsigned)hi << 16) | (unsigned)lo;   // ids < 65536
    }
}

// Phase 4: per-part CSR. Block p scans only its ~8k-edge segment.
__global__ __launch_bounds__(1024) void k_csrB(const unsigned* __restrict__ bucket,
                                               const int* __restrict__ cbase,
                                               int* __restrict__ offsB,
                                               int* __restrict__ adjB) {
    __shared__ int bins[PROWS];
    __shared__ int excl[PROWS];
    __shared__ int cur[PROWS];
    int p = blockIdx.x;
    int segS = cbase[p * NCH];
    int segE = (p + 1 < NPART_B) ? cbase[(p + 1) * NCH] : N_EDGES;
    int r0 = p << PART_SHIFT;
    for (int i = threadIdx.x; i < PROWS; i += 1024) bins[i] = 0;
    __syncthreads();
    for (int j = segS + threadIdx.x; j < segE; j += 1024)
        atomicAdd(&bins[(int)(bucket[j] >> 16) - r0], 1);
    __syncthreads();
    if (threadIdx.x < PROWS) excl[threadIdx.x] = bins[threadIdx.x];
    __syncthreads();
    for (int d = 1; d < PROWS; d <<= 1) {   // Hillis-Steele inclusive scan
        int t = 0;
        if (threadIdx.x < PROWS && threadIdx.x >= d) t = excl[threadIdx.x - d];
        __syncthreads();
        if (threadIdx.x < PROWS) excl[threadIdx.x] += t;
        __syncthreads();
    }
    if (threadIdx.x < PROWS) {
        int st = segS + excl[threadIdx.x] - bins[threadIdx.x];   // exclusive start
        cur[threadIdx.x] = st;
        int v = r0 + threadIdx.x;
        if (v < N_NODES) offsB[v] = st;
    }
    if (p == NPART_B - 1 && threadIdx.x == 0) offsB[N_NODES] = N_EDGES;
    __syncthreads();
    for (int j = segS + threadIdx.x; j < segE; j += 1024) {
        unsigned pk = bucket[j];
        int pos = atomicAdd(&cur[(int)(pk >> 16) - r0], 1);
        adjB[pos] = (int)(pk & 0xFFFFu);
    }
}

// One wave per node: sum/max over both neighbor lists + fused attention mix.
// 8-deep unroll for more outstanding gather loads (latency-bound).
__global__ void k_agg(const float* __restrict__ h, const int* __restrict__ offsA,
                      const int* __restrict__ e1, const int* __restrict__ offsB,
                      const int* __restrict__ adjB, const float* __restrict__ att_w,
                      const float* __restrict__ att_b, float* __restrict__ xbuf) {
    int wid = (blockIdx.x * blockDim.x + threadIdx.x) >> 6;
    int lane = threadIdx.x & 63;
    int sA = offsA[wid], eA = offsA[wid + 1];
    int sB = offsB[wid], eB = offsB[wid + 1];
    float sum = 0.f, mx = -FLT_MAX;
    for (int pass = 0; pass < 2; ++pass) {
        const int* lst = pass ? adjB : e1;
        int e = pass ? sB : sA;
        int end = pass ? eB : eA;
        for (; e + 8 <= end; e += 8) {
            int c0 = lst[e],     c1 = lst[e + 1], c2 = lst[e + 2], c3 = lst[e + 3];
            int c4 = lst[e + 4], c5 = lst[e + 5], c6 = lst[e + 6], c7 = lst[e + 7];
            float v0 = h[c0 * D + lane];
            float v1 = h[c1 * D + lane];
            float v2 = h[c2 * D + lane];
            float v3 = h[c3 * D + lane];
            float v4 = h[c4 * D + lane];
            float v5 = h[c5 * D + lane];
            float v6 = h[c6 * D + lane];
            float v7 = h[c7 * D + lane];
            sum += ((v0 + v1) + (v2 + v3)) + ((v4 + v5) + (v6 + v7));
            mx = fmaxf(mx, fmaxf(fmaxf(fmaxf(v0, v1), fmaxf(v2, v3)),
                                 fmaxf(fmaxf(v4, v5), fmaxf(v6, v7))));
        }
        for (; e < end; ++e) {
            float v = h[lst[e] * D + lane];
            sum += v;
            mx = fmaxf(mx, v);
        }
    }
    if ((eA - sA) + (eB - sB) == 0) mx = 0.f;

    float aw00 = att_w[lane * 2 + 0], aw01 = att_w[lane * 2 + 1];
    float aw10 = att_w[(D + lane) * 2 + 0], aw11 = att_w[(D + lane) * 2 + 1];
    float p0 = sum * aw00 + mx * aw10;
    float p1 = sum * aw01 + mx * aw11;
    for (int o = 32; o > 0; o >>= 1) {
        p0 += __shfl_xor(p0, o);
        p1 += __shfl_xor(p1, o);
    }
    float s0 = p0 + att_b[0], s1 = p1 + att_b[1];
    float m = fmaxf(s0, s1);
    float e0v = expf(s0 - m), e1v = expf(s1 - m);
    float inv = 1.f / (e0v + e1v);
    float w0 = e0v * inv, w1 = e1v * inv;
    xbuf[wid * D + lane] = h[wid * D + lane] + w0 * sum + w1 * mx;
}

// Fused 3-layer MLP, LDS-free. One wave owns 16 rows; weights live in 64 VGPRs
// per lane (w[k][lane]); x[r][k] broadcasts via v_readlane (const index after
// unroll) feeding v_fmac. Layer outputs stay distributed lane=col, which is
// exactly the layout the next layer's readlane-broadcast needs.
// xbuf aliases out: each wave reads only its own 16 rows before writing them.
__global__ __launch_bounds__(256) void k_dense(const float* __restrict__ xbuf,
        const float* __restrict__ w1, const float* __restrict__ b1,
        const float* __restrict__ w2, const float* __restrict__ b2,
        const float* __restrict__ w3, const float* __restrict__ b3,
        float* __restrict__ out) {
    int gwave = (blockIdx.x * blockDim.x + threadIdx.x) >> 6;
    int lane  = threadIdx.x & 63;
    int r0 = gwave * 16;
    if (r0 >= N_NODES) return;   // 3125 full groups (50000 = 16*3125)

    float w[64];
    // Layer 1 weights: lane holds w1[k][lane]
#pragma unroll
    for (int k = 0; k < 64; ++k) w[k] = w1[(k << 6) + lane];

    float x16[16];
#pragma unroll
    for (int r = 0; r < 16; ++r) x16[r] = xbuf[(size_t)(r0 + r) * 64 + lane];

    float y[16];
    float bias = b1[lane];
#pragma unroll
    for (int r = 0; r < 16; ++r) {
        float a = bias;
#pragma unroll
        for (int k = 0; k < 64; ++k) a += lane_bcast(x16[r], k) * w[k];
        y[r] = fmaxf(a, 0.f);
    }

#pragma unroll
    for (int k = 0; k < 64; ++k) w[k] = w2[(k << 6) + lane];
    bias = b2[lane];
#pragma unroll
    for (int r = 0; r < 16; ++r) {
        float a = bias;
#pragma unroll
        for (int k = 0; k < 64; ++k) a += lane_bcast(y[r], k) * w[k];
        x16[r] = fmaxf(a, 0.f);
    }

#pragma unroll
    for (int k = 0; k < 64; ++k) w[k] = w3[(k << 6) + lane];
    bias = b3[lane];
#pragma unroll
    for (int r = 0; r < 16; ++r) {
        float a = bias;
#pragma unroll
        for (int k = 0; k < 64; ++k) a += lane_bcast(x16[r], k) * w[k];
        out[(size_t)(r0 + r) * 64 + lane] = a;
    }
}

extern "C" void kernel_launch(void* const* d_in, const int* in_sizes, int n_in,
                              void* d_out, int out_size, void* d_ws, size_t ws_size,
                              hipStream_t stream) {
    const float* h     = (const float*)d_in[0];
    const int*   ei    = (const int*)d_in[1];
    const float* att_w = (const float*)d_in[2];
    const float* att_b = (const float*)d_in[3];
    const float* w1    = (const float*)d_in[4];
    const float* b1    = (const float*)d_in[5];
    const float* w2    = (const float*)d_in[6];
    const float* b2    = (const float*)d_in[7];
    const float* w3    = (const float*)d_in[8];
    const float* b3    = (const float*)d_in[9];
    float* out = (float*)d_out;

    const int* e0 = ei;             // lo, sorted non-decreasing
    const int* e1 = ei + N_EDGES;   // hi

    char* ws = (char*)d_ws;
    size_t off = 0;
    auto alloc = [&](size_t bytes) {
        char* p = ws + off;
        off = align_up(off + bytes, 256);
        return p;
    };
    int* offsA       = (int*)alloc((size_t)(N_NODES + 1) * 4);
    int* countsG     = (int*)alloc((size_t)CNT_LEN * 4);
    int* cbase       = (int*)alloc((size_t)(CNT_LEN + 1) * 4);
    int* bsum        = (int*)alloc(128 * 4);
    unsigned* bucket = (unsigned*)alloc((size_t)N_EDGES * 4);
    int* offsB       = (int*)alloc((size_t)(N_NODES + 1) * 4);
    int* adjB        = (int*)alloc((size_t)N_EDGES * 4);
    float* xbuf      = out;   // k_dense reads only its own rows before writing

    int nbc = CNT_LEN / 1024;   // 98 exactly
    k_offsA  <<<(N_NODES + 256) / 256, 256, 0, stream>>>(e0, offsA);
    k_count  <<<NCH, 256, 0, stream>>>(e1, countsG);
    k_scan1  <<<nbc, 1024, 0, stream>>>(countsG, cbase, bsum, CNT_LEN);
    k_scan2  <<<1, 128, 0, stream>>>(bsum, nbc);
    k_scan3  <<<(CNT_LEN + 255) / 256, 256, 0, stream>>>(cbase, bsum, CNT_LEN);
    k_scatter<<<NCH, 256, 0, stream>>>(e0, e1, cbase, bucket);
    k_csrB   <<<NPART_B, 1024, 0, stream>>>(bucket, cbase, offsB, adjB);
    k_agg    <<<(N_NODES * 64) / 256, 256, 0, stream>>>(h, offsA, e1, offsB, adjB,
                                                        att_w, att_b, xbuf);
    // 3125 wave-groups of 16 rows, 4 waves/block -> 782 blocks
    k_dense  <<<(3125 + 3) / 4, 256, 0, stream>>>(xbuf, w1, b1, w2, b2, w3, b3, out);
}